// Round 15
// baseline (186.898 us; speedup 1.0000x reference)
//
#include <hip/hip_runtime.h>
#include <math.h>

// ExplaiNN fused forward: B=128, N=300, L=600, K=19, C1=100, PS=7
// LC=582, LP=83, NC=2
#define EPS_ 1e-5f

typedef _Float16 half8 __attribute__((ext_vector_type(8)));
typedef float floatx4 __attribute__((ext_vector_type(4)));

// ---------------------------------------------------------------------------
// kW: pack conv weights to fp16 wT[304][96]: k = c*24+kk (kk<19 real, pad 0;
// n>=300 pad 0). Rows 192B -> every lane quad-load 16B-aligned for B-frags.
// ---------------------------------------------------------------------------
__global__ __launch_bounds__(256) void kW(const float* __restrict__ conv_w,
                                          unsigned short* __restrict__ wT) {
    const int idx = blockIdx.x * 256 + threadIdx.x;
    if (idx >= 304 * 96) return;
    const int n = idx / 96, k = idx - n * 96;
    const int c = k / 24, kk = k - c * 24;
    float v = (n < 300 && kk < 19) ? conv_w[n * 76 + c * 19 + kk] : 0.f;
    union { _Float16 h; unsigned short u; } cv;
    cv.h = (_Float16)v;                 // RTE
    wT[idx] = cv.u;
}

// ---------------------------------------------------------------------------
// kM: conv1d via fp16 MFMA + bias + bn1 + exp + maxpool(7,7).
// kA's fp32-VALU path plateaued at 44-47us across 6 structures (issue floor
// ~26us + latency). This moves the conv to the matrix pipe: im2col GEMM
// D[t][n] = sum_k A[t][k] B[k][n], K=76 padded to 96 (3 x K32 steps).
// Layouts (m89/m91-verified): A[m=lane&15][k=quad*8+j] (8 contiguous t+kk
// -> built from LDS fp32 x-stage via v_cvt_f16_f32, RTE);
// B[k=quad*8+j][n=lane&15] = wT row loads (16B aligned, 3/block, reused);
// D[row=quad*4+r][col=lane&15] -> LDS dbuf[col][t] (pad 116) -> pool7+exp.
// Precision: fp16 rel ~5e-4 -> output absmax ~0.1 << 0.47 threshold.
// grid 128*24 x 64 (1 wave): id = b*24+nt, 24%8==0 -> all b of one nt on
// the same XCD (pooled line assembly, proven since R5). nt>=19 exits.
// 6 t-chunks of 112 (7 m-tiles); x LDS-padded to 704 (zeros past 600) so
// chunk-5 tile reads stay in-bounds; pools p<=82 only read real t<=580.
// ---------------------------------------------------------------------------
__global__ __launch_bounds__(64) void kM(
        const float* __restrict__ x,        // [128][4][600]
        const unsigned short* __restrict__ wT, // [304][96] fp16
        const float* __restrict__ conv_b,
        const float* __restrict__ g1, const float* __restrict__ b1,
        const float* __restrict__ m1, const float* __restrict__ v1,
        float* __restrict__ pooled)         // [300][83][128]
{
    const int id = blockIdx.x;              // b*24 + nt
    const int b  = id / 24;
    const int nt = id - b * 24;
    if (nt >= 19) return;
    const int lane = threadIdx.x;
    const int ln   = lane & 15;
    const int quad = lane >> 4;
    const int n0   = nt * 16;

    __shared__ float xs[4 * 704];           // fp32 x stage, zero-padded
    __shared__ float dbuf[16 * 116];        // D tile [col][t], pad 116

    for (int i = lane; i < 4 * 704; i += 64) {
        const int c = i / 704, t = i - c * 704;
        xs[i] = (t < 600) ? x[b * 2400 + c * 600 + t] : 0.f;
    }

    // B-fragments: 3 k-steps, each 8 fp16 = one aligned 16B load, reused
    half8 bf[3];
    {
        const unsigned short* wrow = wT + (n0 + ln) * 96 + quad * 8;
        #pragma unroll
        for (int s = 0; s < 3; ++s) {
            union { int4 i; half8 h; } u;
            u.i = *reinterpret_cast<const int4*>(wrow + 32 * s);
            bf[s] = u.h;
        }
    }

    // per-quad (c, kk0) for each k-step: kg0 = 32s + 8*quad
    int cS[3], oS[3];
    #pragma unroll
    for (int s = 0; s < 3; ++s) {
        const int kg0 = 32 * s + 8 * quad;
        cS[s] = kg0 / 24; oS[s] = kg0 - cS[s] * 24;
    }

    // bn1 fold for this lane's 4 pooling columns (nq = lane&3)
    const int nq = lane & 3;
    float A1w[4], B1w[4];
    #pragma unroll
    for (int w = 0; w < 4; ++w) {
        const int n = n0 + 4 * nq + w;
        const int nc = (n < 300) ? n : 299;
        A1w[w] = g1[nc] * rsqrtf(v1[nc] + EPS_);
        B1w[w] = fmaf(A1w[w], conv_b[nc] - m1[nc], b1[nc]);
    }
    __syncthreads();

    for (int ci = 0; ci < 6; ++ci) {
        const int t0 = 112 * ci;
        #pragma unroll 1
        for (int mt = 0; mt < 7; ++mt) {
            const int tb = t0 + 16 * mt + ln;   // this lane's A row (t)
            floatx4 acc = {0.f, 0.f, 0.f, 0.f};
            #pragma unroll
            for (int s = 0; s < 3; ++s) {
                const float* px = &xs[cS[s] * 704 + tb + oS[s]];
                half8 af;
                #pragma unroll
                for (int j = 0; j < 8; ++j)
                    af[j] = (_Float16)px[j];    // v_cvt_f16_f32 (RTE)
                acc = __builtin_amdgcn_mfma_f32_16x16x32_f16(af, bf[s], acc,
                                                             0, 0, 0);
            }
            float* dp = &dbuf[ln * 116 + 16 * mt + quad * 4];
            float4 dv = make_float4(acc[0], acc[1], acc[2], acc[3]);
            *reinterpret_cast<float4*>(dp) = dv;
        }
        __syncthreads();
        // pooling: lane = pl*? -> pl = lane>>2 (pool), nq = lane&3 (4 cols)
        const int pl = lane >> 2;
        const int npool = (ci < 5) ? 16 : 3;    // ci=5: pools 80..82 only
        if (pl < npool) {
            const int pg = 16 * ci + pl;
            #pragma unroll
            for (int w = 0; w < 4; ++w) {
                const int n = n0 + 4 * nq + w;
                if (n < 300) {
                    const float* dq = &dbuf[(4 * nq + w) * 116 + 7 * pl];
                    float mx = -INFINITY;       // exp monotone: max first
                    #pragma unroll
                    for (int q = 0; q < 7; ++q)
                        mx = fmaxf(mx, fmaf(A1w[w], dq[q], B1w[w]));
                    pooled[((size_t)n * 83 + pg) * 128 + b] = __expf(mx);
                }
            }
        }
        __syncthreads();
    }
}

// ---------------------------------------------------------------------------
// kB: fc1(K=83) + bn2 + relu + fc2 + bn3 + relu.  UNCHANGED from R14
// (passed; 600 blocks -> 2.3 blocks/CU; stride-116 LDS staging).
// ---------------------------------------------------------------------------
__global__ __launch_bounds__(256, 2) void kB(
        const float* __restrict__ pooled,   // [300][83][128]
        const float* __restrict__ fc1w,     // [300][100][83]
        const float* __restrict__ fc1b,     // [300][100]
        const float* __restrict__ g2, const float* __restrict__ b2,
        const float* __restrict__ m2, const float* __restrict__ v2,
        const float* __restrict__ fc2w,     // [300][100]
        const float* __restrict__ fc2b,     // [300]
        const float* __restrict__ g3, const float* __restrict__ b3,
        const float* __restrict__ m3, const float* __restrict__ v3,
        float* __restrict__ sout)           // [300][128]
{
    __shared__ __align__(16) float sW[83 * 116];    // 38.5 KB
    __shared__ float sRed[4][64];
    const int id  = blockIdx.x;             // 0..599
    const int n   = id >> 1;
    const int bh  = id & 1;
    const int tid = threadIdx.x;

    {
        const float* src = fc1w + (size_t)n * 8300;
        for (int i = tid; i < 8300; i += 256) {
            const int h = i / 83, p = i - h * 83;
            sW[p * 116 + h] = src[i];
        }
        for (int i = tid; i < 83 * 16; i += 256) {
            const int p = i / 16, h = 100 + (i - p * 16);
            sW[p * 116 + h] = 0.f;
        }
    }
    __syncthreads();

    const int lane = tid & 63;
    const int wv   = __builtin_amdgcn_readfirstlane(tid >> 6);
    const int h0   = wv * 28;
    const int bb   = bh * 64 + lane;

    const float* pp = pooled + (size_t)n * 83 * 128 + bb;

    float acc[28];
    #pragma unroll
    for (int j = 0; j < 28; ++j) acc[j] = 0.f;

    #pragma unroll 4
    for (int p = 0; p < 83; ++p) {
        const float pv = pp[p * 128];
        const float* wrow = sW + p * 116 + h0;
        #pragma unroll
        for (int jq = 0; jq < 7; ++jq) {
            const float4 w = *reinterpret_cast<const float4*>(wrow + 4 * jq);
            acc[jq * 4 + 0] = fmaf(w.x, pv, acc[jq * 4 + 0]);
            acc[jq * 4 + 1] = fmaf(w.y, pv, acc[jq * 4 + 1]);
            acc[jq * 4 + 2] = fmaf(w.z, pv, acc[jq * 4 + 2]);
            acc[jq * 4 + 3] = fmaf(w.w, pv, acc[jq * 4 + 3]);
        }
    }

    const int nh = (wv < 3) ? 28 : 16;
    float part = 0.f;
    for (int j = 0; j < nh; ++j) {
        const int hi = n * 100 + h0 + j;
        const float A2 = g2[hi] * rsqrtf(v2[hi] + EPS_);
        const float C2 = fmaf(A2, fc1b[hi] - m2[hi], b2[hi]);
        part = fmaf(fmaxf(fmaf(A2, acc[j], C2), 0.f), fc2w[hi], part);
    }
    sRed[wv][lane] = part;
    __syncthreads();

    if (tid < 64) {
        float s = sRed[0][tid] + sRed[1][tid] + sRed[2][tid] + sRed[3][tid];
        s += fc2b[n];
        const float A3 = g3[n] * rsqrtf(v3[n] + EPS_);
        const float z = fmaf(A3, s - m3[n], b3[n]);
        sout[n * 128 + bh * 64 + tid] = fmaxf(z, 0.f);
    }
}

// ---------------------------------------------------------------------------
// kC: out[b,c] = sum_n sout[n][b] * fw[c][n] + fb[c].  grid 128 x 64.
// ---------------------------------------------------------------------------
__global__ __launch_bounds__(64) void kC(
        const float* __restrict__ sout,     // [300][128]
        const float* __restrict__ fw,       // [2][300]
        const float* __restrict__ fb,
        float* __restrict__ out)            // [128][2]
{
    const int b = blockIdx.x, t = threadIdx.x;
    float a0 = 0.f, a1 = 0.f;
    for (int nn = t; nn < 300; nn += 64) {
        const float v = sout[nn * 128 + b];
        a0 = fmaf(v, fw[nn], a0);
        a1 = fmaf(v, fw[300 + nn], a1);
    }
    #pragma unroll
    for (int off = 32; off > 0; off >>= 1) {
        a0 += __shfl_xor(a0, off, 64);
        a1 += __shfl_xor(a1, off, 64);
    }
    if (t == 0) {
        out[b * 2 + 0] = a0 + fb[0];
        out[b * 2 + 1] = a1 + fb[1];
    }
}

extern "C" void kernel_launch(void* const* d_in, const int* in_sizes, int n_in,
                              void* d_out, int out_size, void* d_ws, size_t ws_size,
                              hipStream_t stream) {
    const float* x      = (const float*)d_in[0];
    const float* conv_w = (const float*)d_in[1];
    const float* conv_b = (const float*)d_in[2];
    const float* g1 = (const float*)d_in[3];
    const float* b1 = (const float*)d_in[4];
    const float* m1 = (const float*)d_in[5];
    const float* v1 = (const float*)d_in[6];
    const float* fc1_w = (const float*)d_in[7];
    const float* fc1_b = (const float*)d_in[8];
    const float* g2 = (const float*)d_in[9];
    const float* b2 = (const float*)d_in[10];
    const float* m2 = (const float*)d_in[11];
    const float* v2 = (const float*)d_in[12];
    const float* fc2_w = (const float*)d_in[13];
    const float* fc2_b = (const float*)d_in[14];
    const float* g3 = (const float*)d_in[15];
    const float* b3 = (const float*)d_in[16];
    const float* m3 = (const float*)d_in[17];
    const float* v3 = (const float*)d_in[18];
    const float* fw = (const float*)d_in[19];
    const float* fb = (const float*)d_in[20];
    float* out = (float*)d_out;

    float* pooled = (float*)d_ws;                        // 300*83*128 = 3187200
    float* sout   = pooled + (size_t)300 * 83 * 128;     // 300*128    = 38400
    unsigned short* wT = (unsigned short*)(sout + 38400);// 304*96 fp16 (16B-aligned)
    // total ws: ~12.9 MB

    kW<<<114, 256, 0, stream>>>(conv_w, wT);
    kM<<<128 * 24, 64, 0, stream>>>(x, wT, conv_b, g1, b1, m1, v1, pooled);
    kB<<<600, 256, 0, stream>>>(pooled, fc1_w, fc1_b, g2, b2, m2, v2,
                                fc2_w, fc2_b, g3, b3, m3, v3, sout);
    kC<<<128, 64, 0, stream>>>(sout, fw, fb, out);
}

// Round 16
// 173.557 us; speedup vs baseline: 1.0769x; 1.0769x over previous
//
#include <hip/hip_runtime.h>
#include <math.h>

// ExplaiNN fused forward: B=128, N=300, L=600, K=19, C1=100, PS=7
// LC=582, LP=83, NC=2
#define EPS_ 1e-5f

// ---------------------------------------------------------------------------
// kP: cw4[c][kq][n][0..3] float4 conv-weight pack for kA (20 blocks, ~2us).
// ---------------------------------------------------------------------------
__global__ __launch_bounds__(256) void kP(const float* __restrict__ conv_w,
                                          float* __restrict__ cw4) {
    const int cq = blockIdx.x;              // 0..19
    const int c  = cq / 5;
    const int kq = cq - c * 5;
    for (int n = threadIdx.x; n < 300; n += 256) {
        float4 v;
        const int k0 = 4 * kq;
        v.x = (k0 + 0 < 19) ? conv_w[n * 76 + c * 19 + k0 + 0] : 0.f;
        v.y = (k0 + 1 < 19) ? conv_w[n * 76 + c * 19 + k0 + 1] : 0.f;
        v.z = (k0 + 2 < 19) ? conv_w[n * 76 + c * 19 + k0 + 2] : 0.f;
        v.w = (k0 + 3 < 19) ? conv_w[n * 76 + c * 19 + k0 + 3] : 0.f;
        reinterpret_cast<float4*>(cw4)[(c * 5 + kq) * 300 + n] = v;
    }
}

// ---------------------------------------------------------------------------
// kA: conv1d(4ch,K=19) + bias + bn1 + exp + maxpool(7,7).  R9-EXACT (best
// measured 44.3-45.5us over 3 runs; VGPR=32, VALUBusy ~61%). R15's fp16
// MFMA port (kM) lost: 56us at MfmaUtil 3% -- im2col fragment gather (8
// ds_read+cvt per MFMA per lane) swamps the matrix pipe. Vector path it is.
// ---------------------------------------------------------------------------
__global__ __launch_bounds__(64) void kA(
        const float* __restrict__ x,        // [128][4][600]
        const float* __restrict__ cw4,      // [4][5][300][4]
        const float* __restrict__ conv_b,
        const float* __restrict__ g1, const float* __restrict__ b1,
        const float* __restrict__ m1, const float* __restrict__ v1,
        float* __restrict__ pooled)         // [300][83][128]
{
    const int id  = blockIdx.x;             // b*112 + sub
    const int b   = id / 112;
    const int sub = id - b * 112;
    if (sub >= 105) return;
    const int ng  = sub / 21;
    const int pc  = sub - ng * 21;
    const int p0c = pc * 4;
    const int p0  = (p0c > 79) ? 79 : p0c;  // p=79 done twice, same value
    const int lane = threadIdx.x;
    const int n   = ng * 64 + lane;
    const int nc  = (n < 300) ? n : 299;

    const float4* w4 = reinterpret_cast<const float4*>(cw4);

    float acc[28];
    #pragma unroll
    for (int i = 0; i < 28; ++i) acc[i] = 0.f;

    #pragma unroll 1
    for (int c = 0; c < 4; ++c) {
        const float* xc = x + b * 2400 + c * 600 + 7 * p0;  // uniform -> s_load
        float xw[46];
        #pragma unroll
        for (int j = 0; j < 46; ++j) xw[j] = xc[j];
        #pragma unroll
        for (int kq = 0; kq < 5; ++kq) {
            const float4 wv = w4[(c * 5 + kq) * 300 + nc];  // 4 k's, coalesced
            const int ni = (kq == 4) ? 3 : 4;               // k<19
            #pragma unroll
            for (int i = 0; i < ni; ++i) {
                const int k = 4 * kq + i;
                const float wvv = (i == 0) ? wv.x : (i == 1) ? wv.y
                                : (i == 2) ? wv.z : wv.w;
                #pragma unroll
                for (int p = 0; p < 4; ++p)
                    #pragma unroll
                    for (int q = 0; q < 7; ++q)
                        acc[p * 7 + q] = fmaf(xw[7 * p + q + k], wvv,
                                              acc[p * 7 + q]);
            }
        }
    }

    const float A1 = g1[nc] * rsqrtf(v1[nc] + EPS_);
    const float B1 = fmaf(A1, conv_b[nc] - m1[nc], b1[nc]);
    if (n < 300) {
        float* op = pooled + ((size_t)n * 83 + p0) * 128 + b;
        #pragma unroll
        for (int p = 0; p < 4; ++p) {
            float mx = -INFINITY;           // exp monotone: max before exp
            #pragma unroll
            for (int q = 0; q < 7; ++q)
                mx = fmaxf(mx, fmaf(A1, acc[p * 7 + q], B1));
            op[p * 128] = __expf(mx);
        }
    }
}

// ---------------------------------------------------------------------------
// kB: fc1(K=83) + bn2 + relu + fc2 partial.
// R14's kB (~28us est.) was grid-limited: 600 blocks x 4 waves = 2.34
// waves/SIMD, 83 serial load batches/wave mostly exposed. Now block =
// (n, b-half, h-HALF): grid 1200 x 256 -> 4800 waves (4.7/SIMD, 2x hiding).
// Each block stages only its 50-h half: sW[83][60] = 19.9KB (stride 60:
// write banks 28p%32 -> 8-way ~free [m136]; reads broadcast b32, conflict-
// free). 4 waves own h-chunks {13,13,13,11}. lane = b: 1 coalesced pooled
// load per p. acc[13] -> high occupancy. fc2 sum spans 2 blocks -> each
// writes a PARTIAL to sp[hq][n][b]; kC absorbs fc2b+bn3+relu.
// ---------------------------------------------------------------------------
__global__ __launch_bounds__(256) void kB(
        const float* __restrict__ pooled,   // [300][83][128]
        const float* __restrict__ fc1w,     // [300][100][83]
        const float* __restrict__ fc1b,     // [300][100]
        const float* __restrict__ g2, const float* __restrict__ b2,
        const float* __restrict__ m2, const float* __restrict__ v2,
        const float* __restrict__ fc2w,     // [300][100]
        float* __restrict__ sp)             // [2][300][128] fc2 partials
{
    __shared__ float sW[83 * 60];           // 19.9 KB
    __shared__ float sRed[4][64];
    const int id  = blockIdx.x;             // 0..1199
    const int n   = id >> 2;
    const int rem = id & 3;
    const int bh  = rem >> 1;
    const int hq  = rem & 1;                // h-half: h in [hq*50, hq*50+50)
    const int tid = threadIdx.x;

    {   // stage this h-half: coalesced reads; stride-60 writes (8-way, ~free)
        const float* src = fc1w + (size_t)n * 8300 + hq * 50 * 83;
        for (int i = tid; i < 4150; i += 256) {
            const int h = i / 83, p = i - h * 83;
            sW[p * 60 + h] = src[i];
        }
        for (int i = tid; i < 830; i += 256) {   // zero pad h'=50..59
            const int p = i / 10, h = 50 + (i - p * 10);
            sW[p * 60 + h] = 0.f;
        }
    }
    __syncthreads();

    const int lane = tid & 63;
    const int wv   = __builtin_amdgcn_readfirstlane(tid >> 6);  // 0..3
    const int h0   = wv * 13;               // local: 0,13,26,39
    const int nh   = (wv < 3) ? 13 : 11;    // 13*3+11 = 50
    const int bb   = bh * 64 + lane;

    const float* pp = pooled + (size_t)n * 83 * 128 + bb;

    float acc[13];
    #pragma unroll
    for (int j = 0; j < 13; ++j) acc[j] = 0.f;

    #pragma unroll 4
    for (int p = 0; p < 83; ++p) {
        const float pv = pp[p * 128];       // coalesced 256B
        const float* wrow = sW + p * 60 + h0;
        #pragma unroll
        for (int j = 0; j < 13; ++j)        // broadcast b32 reads
            acc[j] = fmaf(wrow[j], pv, acc[j]);
    }

    // bn2 + relu + fc2 partial over this wave's real h's (params uniform)
    const int hbase = n * 100 + hq * 50 + h0;
    float part = 0.f;
    for (int j = 0; j < nh; ++j) {
        const int hi = hbase + j;
        const float A2 = g2[hi] * rsqrtf(v2[hi] + EPS_);
        const float C2 = fmaf(A2, fc1b[hi] - m2[hi], b2[hi]);
        part = fmaf(fmaxf(fmaf(A2, acc[j], C2), 0.f), fc2w[hi], part);
    }
    sRed[wv][lane] = part;
    __syncthreads();

    if (tid < 64) {
        const float s = sRed[0][tid] + sRed[1][tid] + sRed[2][tid] + sRed[3][tid];
        sp[((size_t)hq * 300 + n) * 128 + bh * 64 + tid] = s;
    }
}

// ---------------------------------------------------------------------------
// kC: combine fc2 partials + fc2b + bn3 + relu, then final [300]x[2] matmul.
// out[b,c] = sum_n relu(bn3(sp0+sp1+fc2b)) * fw[c][n] + fb[c].  128 x 64.
// ---------------------------------------------------------------------------
__global__ __launch_bounds__(64) void kC(
        const float* __restrict__ sp,       // [2][300][128]
        const float* __restrict__ fc2b,
        const float* __restrict__ g3, const float* __restrict__ b3,
        const float* __restrict__ m3, const float* __restrict__ v3,
        const float* __restrict__ fw,       // [2][300]
        const float* __restrict__ fb,
        float* __restrict__ out)            // [128][2]
{
    const int b = blockIdx.x, t = threadIdx.x;
    float a0 = 0.f, a1 = 0.f;
    for (int nn = t; nn < 300; nn += 64) {
        const float s = sp[nn * 128 + b] + sp[(300 + nn) * 128 + b] + fc2b[nn];
        const float A3 = g3[nn] * rsqrtf(v3[nn] + EPS_);
        const float z = fmaxf(fmaf(A3, s - m3[nn], b3[nn]), 0.f);
        a0 = fmaf(z, fw[nn], a0);
        a1 = fmaf(z, fw[300 + nn], a1);
    }
    #pragma unroll
    for (int off = 32; off > 0; off >>= 1) {
        a0 += __shfl_xor(a0, off, 64);
        a1 += __shfl_xor(a1, off, 64);
    }
    if (t == 0) {
        out[b * 2 + 0] = a0 + fb[0];
        out[b * 2 + 1] = a1 + fb[1];
    }
}

extern "C" void kernel_launch(void* const* d_in, const int* in_sizes, int n_in,
                              void* d_out, int out_size, void* d_ws, size_t ws_size,
                              hipStream_t stream) {
    const float* x      = (const float*)d_in[0];
    const float* conv_w = (const float*)d_in[1];
    const float* conv_b = (const float*)d_in[2];
    const float* g1 = (const float*)d_in[3];
    const float* b1 = (const float*)d_in[4];
    const float* m1 = (const float*)d_in[5];
    const float* v1 = (const float*)d_in[6];
    const float* fc1_w = (const float*)d_in[7];
    const float* fc1_b = (const float*)d_in[8];
    const float* g2 = (const float*)d_in[9];
    const float* b2 = (const float*)d_in[10];
    const float* m2 = (const float*)d_in[11];
    const float* v2 = (const float*)d_in[12];
    const float* fc2_w = (const float*)d_in[13];
    const float* fc2_b = (const float*)d_in[14];
    const float* g3 = (const float*)d_in[15];
    const float* b3 = (const float*)d_in[16];
    const float* m3 = (const float*)d_in[17];
    const float* v3 = (const float*)d_in[18];
    const float* fw = (const float*)d_in[19];
    const float* fb = (const float*)d_in[20];
    float* out = (float*)d_out;

    float* pooled = (float*)d_ws;                        // 300*83*128 = 3187200
    float* sp     = pooled + (size_t)300 * 83 * 128;     // 2*300*128  = 76800
    float* cw4    = sp + 76800;                          // 4*5*300*4  = 24000
    // total ws: ~13.2 MB

    kP<<<20, 256, 0, stream>>>(conv_w, cw4);
    kA<<<128 * 112, 64, 0, stream>>>(x, cw4, conv_b, g1, b1, m1, v1, pooled);
    kB<<<1200, 256, 0, stream>>>(pooled, fc1_w, fc1_b, g2, b2, m2, v2,
                                 fc2_w, sp);
    kC<<<128, 64, 0, stream>>>(sp, fc2_b, g3, b3, m3, v3, fw, fb, out);
}